// Round 3
// baseline (109.296 us; speedup 1.0000x reference)
//
#include <hip/hip_runtime.h>

// FSUMatMul one-cycle. Exact identity: with in_f = scale_carry = 2048 and
// DEPTH=12 (bound 4095 > 2048), the emitted bit is
//   out[b,o] = (sum_k XNOR(x[b,k], path[o,k]) == in_f)
//            = (x row b bit-identical to path row o, all 2048 bits).
//
// Fast path compares only the first 64 bits (word 0) of each row, packed by
// a tiny kernel (2 MB of reads). If word 0 matches (prob ~2^-64 per pair),
// a deferred slow path re-verifies the remaining 1984 bits straight from the
// pristine x/w in global memory — exact for ANY input, ~never executed.
//
// Controllable traffic: pack reads 2 MB; cmp writes the mandatory 67 MB out.
// Everything else in the timed graph is harness reset (fills + restores).

#define BATCH 4096
#define INF   2048
#define OUTF  4096

typedef float f32x4 __attribute__((ext_vector_type(4)));
typedef unsigned long long u64;

// One wave packs the first 64 columns of one row (x or w->path) via ballot.
// ids [0, BATCH) -> x rows, [BATCH, BATCH+OUTF) -> w rows.
__global__ __launch_bounds__(256) void pack0_kernel(
    const float* __restrict__ x, const float* __restrict__ w,
    const float* __restrict__ rng,
    u64* __restrict__ xp0, u64* __restrict__ pp0)
{
    const int lane = threadIdx.x & 63;
    const int wav  = threadIdx.x >> 6;
    const int id   = blockIdx.x * 4 + wav;          // wave-uniform

    if (id < BATCH) {
        const float v = x[(size_t)id * INF + lane]; // 256B coalesced per wave
        const u64 b = __ballot(v != 0.0f);
        if (lane == 0) xp0[id] = b;
    } else {
        const int o = id - BATCH;
        const float v = w[(size_t)o * INF + lane];
        // BinGen/BSGen: source = round((w+1)*0.5*2^WIDTH); path = source > rng.
        // rintf = round-half-even matches jnp.round; *0.5 and *256 exact.
        const float s = rintf((v + 1.0f) * 0.5f * 256.0f);
        const u64 b = __ballot(s > rng[0]);
        if (lane == 0) pp0[o] = b;
    }
}

// out[b, o0..o0+3] per thread; 16 b-rows per block. Branch-free fast path:
// hoist all 16 x-words, then 16 compare + nontemporal float4 stores
// back-to-back. Rare full verification deferred to one trailing branch
// (overwrites the already-stored value), keeping the result exact for ANY
// input without breaking store pipelining.
__global__ __launch_bounds__(256) void cmp_kernel(
    const u64* __restrict__ xp0,
    const u64* __restrict__ pp0,
    const float* __restrict__ x, const float* __restrict__ w,
    const float* __restrict__ rng,
    float* __restrict__ out)
{
    const int tid = threadIdx.x;
    const int o0  = (blockIdx.x * 256 + tid) * 4;
    const int b0  = blockIdx.y * 16;

    // word-0 of 4 consecutive path rows: 32B/thread contiguous -> coalesced
    u64 p[4];
    #pragma unroll
    for (int j = 0; j < 4; ++j) p[j] = pp0[o0 + j];

    // all 16 x-words upfront: independent loads, one wait
    u64 xw[16];
    #pragma unroll
    for (int i = 0; i < 16; ++i) xw[i] = xp0[b0 + i];

    bool hit = false;
    #pragma unroll
    for (int i = 0; i < 16; ++i) {
        const bool e0 = (p[0] == xw[i]);
        const bool e1 = (p[1] == xw[i]);
        const bool e2 = (p[2] == xw[i]);
        const bool e3 = (p[3] == xw[i]);
        hit = hit | e0 | e1 | e2 | e3;
        f32x4 res = { e0 ? 1.0f : 0.0f, e1 ? 1.0f : 0.0f,
                      e2 ? 1.0f : 0.0f, e3 ? 1.0f : 0.0f };
        __builtin_nontemporal_store(
            res, reinterpret_cast<f32x4*>(out + (size_t)(b0 + i) * OUTF + o0));
    }

    if (hit) {                                       // prob ~2^-64 per pair
        const float r = rng[0];
        for (int i = 0; i < 16; ++i) {
            const int b = b0 + i;
            for (int j = 0; j < 4; ++j) {
                if (p[j] != xw[i]) continue;
                const int o = o0 + j;
                bool all = true;
                for (int k = 64; k < INF; ++k) {
                    const bool xb = x[(size_t)b * INF + k] != 0.0f;
                    const bool pb =
                        rintf((w[(size_t)o * INF + k] + 1.0f) * 0.5f * 256.0f) > r;
                    all = all && (xb == pb);
                }
                out[(size_t)b * OUTF + o] = all ? 1.0f : 0.0f;
            }
        }
    }
}

extern "C" void kernel_launch(void* const* d_in, const int* in_sizes, int n_in,
                              void* d_out, int out_size, void* d_ws, size_t ws_size,
                              hipStream_t stream) {
    const float* x   = (const float*)d_in[0];   // (4096, 2048) {0,1}
    const float* w   = (const float*)d_in[1];   // (4096, 2048) [-1,1]
    const float* rng = (const float*)d_in[2];   // scalar 128.0
    float* out = (float*)d_out;                 // (4096, 4096)

    u64* xp0 = (u64*)d_ws;                      // 4096 u64 = 32KB
    u64* pp0 = xp0 + BATCH;                     // 4096 u64 = 32KB

    // 8192 word-0 packs, 4 waves per 256-thread block -> 2048 blocks
    pack0_kernel<<<dim3((BATCH + OUTF) / 4), dim3(256), 0, stream>>>(
        x, w, rng, xp0, pp0);

    // grid: 4 o-tiles (1024 cols each) x 256 b-tiles (16 rows each)
    cmp_kernel<<<dim3(OUTF / 1024, BATCH / 16), dim3(256), 0, stream>>>(
        xp0, pp0, x, w, rng, out);
}